// Round 4
// baseline (32.284 us; speedup 1.0000x reference)
//
#include <hip/hip_runtime.h>

#define B_   16
#define C_   3
#define H_   64
#define W_   64
#define K_   32
#define S_   16
#define OH_  60
#define OW_  60
#define P_   3600
#define IMG  (C_*H_*W_)      // 12288 pixels per batch image
#define XT_FLOATS (IMG*16)   // 196608
#define XT_PAD    4096       // slack for ow/rw overhang reads (helper lanes)

// ---------------- prep kernel: transpose + coefs + base-offset decode ------
// blocks 0..191  : transpose x (B,C,H,W) -> xt (C,H,W,B), 4-way b-split
// blocks 192..195: coef[k][node] = softmax(w_node_k) @ M   (992 gates)
// blocks 196..197: baseA/baseB[k*16+s] from p=0 slice of index arrays
__global__ __launch_bounds__(256) void prep_kernel(
    const float* __restrict__ x,
    const int* __restrict__ ah, const int* __restrict__ aw, const int* __restrict__ ac,
    const int* __restrict__ bh, const int* __restrict__ bw, const int* __restrict__ bc,
    const float* __restrict__ w0, const float* __restrict__ w1,
    const float* __restrict__ w2, const float* __restrict__ w3,
    const float* __restrict__ w4,
    float* __restrict__ xt, float* __restrict__ coef,
    int* __restrict__ baseA, int* __restrict__ baseB)
{
    const int blk = blockIdx.x;
    const int tid = threadIdx.x;

    if (blk < 192) {                     // ---- transpose, b-split 4-way ----
        int idx = blk * 256 + tid;       // 192*256 == 12288*4 exactly
        int chw = idx >> 2;
        int bg  = idx & 3;
        float4 v;
        v.x = x[(bg*4+0) * IMG + chw];
        v.y = x[(bg*4+1) * IMG + chw];
        v.z = x[(bg*4+2) * IMG + chw];
        v.w = x[(bg*4+3) * IMG + chw];
        *(float4*)(xt + (size_t)chw * 16 + bg * 4) = v;
        return;
    }
    if (blk < 196) {                     // ---- coefs ----
        int t = (blk - 192) * 256 + tid;
        if (t >= 31 * K_) return;
        int node = t >> 5;               // 0..30
        int k    = t & 31;
        const float* w; int i;
        if      (node < 16) { w = w0; i = node;      }
        else if (node < 24) { w = w1; i = node - 16; }
        else if (node < 28) { w = w2; i = node - 24; }
        else if (node < 30) { w = w3; i = node - 28; }
        else                { w = w4; i = 0;         }
        const float* src = w + ((size_t)i * K_ + k) * 16;
        float l[16];
        float m = -1e30f;
#pragma unroll
        for (int s = 0; s < 16; ++s) { l[s] = src[s]; m = fmaxf(m, l[s]); }
        float sum = 0.f;
#pragma unroll
        for (int s = 0; s < 16; ++s) { l[s] = expf(l[s] - m); sum += l[s]; }
        float inv = 1.f / sum;
        const float M[16][4] = {
            {0,0,0,0},{0,0,0,1},{0,1,0,-1},{0,1,0,0},
            {0,0,1,-1},{0,0,1,0},{0,1,1,-2},{0,1,1,-1},
            {1,-1,-1,1},{1,-1,-1,2},{1,0,-1,0},{1,0,-1,1},
            {1,-1,0,0},{1,-1,0,1},{1,0,0,-1},{1,0,0,0}};
        float c0 = 0.f, c1 = 0.f, c2 = 0.f, c3 = 0.f;
#pragma unroll
        for (int s = 0; s < 16; ++s) {
            float pr = l[s] * inv;
            c0 += pr * M[s][0]; c1 += pr * M[s][1];
            c2 += pr * M[s][2]; c3 += pr * M[s][3];
        }
        ((float4*)coef)[(size_t)k * 31 + node] = make_float4(c0, c1, c2, c3);
        return;
    }
    {                                    // ---- base offsets (p = 0 slice) ----
        int i = (blk - 196) * 256 + tid;
        if (i >= K_ * S_) return;
        int k = i >> 4, s = i & 15;
        int idx = k * (P_ * 16) + s;     // (k*P + 0)*16 + s
        baseA[i] = (ac[idx] * 4096 + ah[idx] * 64 + aw[idx]) * 16;
        baseB[i] = (bc[idx] * 4096 + bh[idx] * 64 + bw[idx]) * 16;
    }
}

// ---------------- main kernel: structured gather + gate tree ---------------
// grid (oh=60, k=32), 256 threads. lane l in wave wv: ow = wv*16 + (l&15),
// batch-group e = l>>4 (batches 4e..4e+3). Per s each wave's two float4
// gathers form one contiguous 1KB run of xt -> fully coalesced, L2-resident.
__global__ __launch_bounds__(256) void logic_main_kernel(
    const float* __restrict__ xt, const float* __restrict__ coef,
    const int* __restrict__ baseA, const int* __restrict__ baseB,
    float* __restrict__ out)
{
    const int oh = blockIdx.x;
    const int k  = blockIdx.y;
    const int tid = threadIdx.x;

    __shared__ float4 cf[31];
    __shared__ int bA[16], bB[16];
    if (tid < 31)                 cf[tid]      = ((const float4*)coef)[(size_t)k * 31 + tid];
    else if (tid >= 32 && tid < 48) bA[tid-32] = baseA[k * 16 + (tid - 32)];
    else if (tid >= 48 && tid < 64) bB[tid-48] = baseB[k * 16 + (tid - 48)];
    __syncthreads();

    const int l  = tid & 63;
    const int wv = tid >> 6;
    const int ow = wv * 16 + (l & 15);   // 0..63 (>=60 are helper lanes)
    const int e  = l >> 4;               // batch group
    const int pix = (oh * 64 + ow) * 16 + e * 4;

    float v[4][16];                      // [batch-in-group][leaf]
#pragma unroll
    for (int s = 0; s < 16; ++s) {
        float4 av = *(const float4*)(xt + bA[s] + pix);
        float4 bv = *(const float4*)(xt + bB[s] + pix);
        float4 c  = cf[s];
        v[0][s] = c.x + c.y*av.x + c.z*bv.x + c.w*(av.x*bv.x);
        v[1][s] = c.x + c.y*av.y + c.z*bv.y + c.w*(av.y*bv.y);
        v[2][s] = c.x + c.y*av.z + c.z*bv.z + c.w*(av.z*bv.z);
        v[3][s] = c.x + c.y*av.w + c.z*bv.w + c.w*(av.w*bv.w);
    }

    const bool valid = (ow < OW_);
#pragma unroll
    for (int j = 0; j < 4; ++j) {
#pragma unroll
        for (int i = 0; i < 8; ++i) {
            float4 c = cf[16 + i];
            float a = v[j][2*i], b = v[j][2*i+1];
            v[j][i] = c.x + c.y*a + c.z*b + c.w*(a*b);
        }
#pragma unroll
        for (int i = 0; i < 4; ++i) {
            float4 c = cf[24 + i];
            float a = v[j][2*i], b = v[j][2*i+1];
            v[j][i] = c.x + c.y*a + c.z*b + c.w*(a*b);
        }
#pragma unroll
        for (int i = 0; i < 2; ++i) {
            float4 c = cf[28 + i];
            float a = v[j][2*i], b = v[j][2*i+1];
            v[j][i] = c.x + c.y*a + c.z*b + c.w*(a*b);
        }
        float4 c = cf[30];
        float a = v[j][0], b = v[j][1];
        float r = c.x + c.y*a + c.z*b + c.w*(a*b);
        if (valid)
            out[((size_t)(e*4 + j) * K_ + k) * P_ + oh * OW_ + ow] = r;
    }
}

extern "C" void kernel_launch(void* const* d_in, const int* in_sizes, int n_in,
                              void* d_out, int out_size, void* d_ws, size_t ws_size,
                              hipStream_t stream) {
    const float* x  = (const float*)d_in[0];
    const int* ah = (const int*)d_in[1];
    const int* aw = (const int*)d_in[2];
    const int* ac = (const int*)d_in[3];
    const int* bh = (const int*)d_in[4];
    const int* bw = (const int*)d_in[5];
    const int* bc = (const int*)d_in[6];
    const float* w0 = (const float*)d_in[7];
    const float* w1 = (const float*)d_in[8];
    const float* w2 = (const float*)d_in[9];
    const float* w3 = (const float*)d_in[10];
    const float* w4 = (const float*)d_in[11];
    float* out = (float*)d_out;

    float* xt   = (float*)d_ws;                         // 196608 + pad floats
    float* coef = xt + XT_FLOATS + XT_PAD;              // 31*32*4 floats
    int*  baseA = (int*)(coef + 31 * K_ * 4);           // 512 ints
    int*  baseB = baseA + K_ * S_;                      // 512 ints

    prep_kernel<<<198, 256, 0, stream>>>(x, ah, aw, ac, bh, bw, bc,
                                         w0, w1, w2, w3, w4,
                                         xt, coef, baseA, baseB);

    dim3 grid(OH_, K_);
    logic_main_kernel<<<grid, 256, 0, stream>>>(xt, coef, baseA, baseB, out);
}

// Round 5
// 26.210 us; speedup vs baseline: 1.2318x; 1.2318x over previous
//
#include <hip/hip_runtime.h>

#define B_   16
#define C_   3
#define H_   64
#define W_   64
#define K_   32
#define S_   16
#define OH_  60
#define OW_  60
#define P_   3600
#define IMG  (C_*H_*W_)

#define KG   8                  // k's per block
#define NKG  (K_/KG)            // 4 k-groups
#define ROWS (C_*5)             // 15 (c, rh) rows per oh-stripe
#define BPAD 20                 // padded batch stride in floats (banks spread)
#define ROWSTRIDE (W_*BPAD)     // 1280 floats
#define XLDS (ROWS*ROWSTRIDE)   // 19200 floats = 76.8 KB

// Single fused kernel. Block (oh, kg): stages the x-stripe rows
// h = oh..oh+4 (all c, all b) into LDS in b-innermost layout, computes the
// 8 k's soft-gate coefs + base offsets in-block, then evaluates the full
// gate tree reading operands from LDS. Wave wv owns k = kg*8+wv; lane =
// (ow 16, e 4) looping 4 ow-quadrants.
__global__ __launch_bounds__(512) void logic_fused_kernel(
    const float* __restrict__ x,
    const int* __restrict__ ah, const int* __restrict__ aw, const int* __restrict__ ac,
    const int* __restrict__ bh, const int* __restrict__ bw, const int* __restrict__ bc,
    const float* __restrict__ w0, const float* __restrict__ w1,
    const float* __restrict__ w2, const float* __restrict__ w3,
    const float* __restrict__ w4,
    float* __restrict__ out)
{
    __shared__ float  xs[XLDS];
    __shared__ float4 cf[KG * 31];
    __shared__ int    bAi[KG * S_], bBi[KG * S_];

    const int oh  = blockIdx.x;
    const int kg  = blockIdx.y;
    const int tid = threadIdx.x;
    const int l   = tid & 63;
    const int wv  = tid >> 6;           // 0..7

    // ---- stage x stripe: 240 jobs (row=c*5+dh, b); 1 coalesced 256B read each
    for (int job = wv; job < ROWS * B_; job += 8) {
        int b   = job & 15;
        int row = job >> 4;             // c*5 + dh, 0..14
        int c   = row / 5, dh = row - c * 5;
        float v = x[((b * C_ + c) * H_ + (oh + dh)) * W_ + l];
        xs[row * ROWSTRIDE + l * BPAD + b] = v;
    }

    // ---- coefs (threads 0..255) and base offsets (threads 256..511)
    if (tid < 256) {
        int node = tid & 31, kk = tid >> 5;
        if (node < 31) {
            int k = kg * KG + kk;
            const float* w; int i;
            if      (node < 16) { w = w0; i = node;      }
            else if (node < 24) { w = w1; i = node - 16; }
            else if (node < 28) { w = w2; i = node - 24; }
            else if (node < 30) { w = w3; i = node - 28; }
            else                { w = w4; i = 0;         }
            const float* src = w + ((size_t)i * K_ + k) * 16;
            float lg[16];
            float m = -1e30f;
#pragma unroll
            for (int s = 0; s < 16; ++s) { lg[s] = src[s]; m = fmaxf(m, lg[s]); }
            float sum = 0.f;
#pragma unroll
            for (int s = 0; s < 16; ++s) { lg[s] = expf(lg[s] - m); sum += lg[s]; }
            float inv = 1.f / sum;
            const float M[16][4] = {
                {0,0,0,0},{0,0,0,1},{0,1,0,-1},{0,1,0,0},
                {0,0,1,-1},{0,0,1,0},{0,1,1,-2},{0,1,1,-1},
                {1,-1,-1,1},{1,-1,-1,2},{1,0,-1,0},{1,0,-1,1},
                {1,-1,0,0},{1,-1,0,1},{1,0,0,-1},{1,0,0,0}};
            float c0 = 0.f, c1 = 0.f, c2 = 0.f, c3 = 0.f;
#pragma unroll
            for (int s = 0; s < 16; ++s) {
                float pr = lg[s] * inv;
                c0 += pr * M[s][0]; c1 += pr * M[s][1];
                c2 += pr * M[s][2]; c3 += pr * M[s][3];
            }
            cf[kk * 31 + node] = make_float4(c0, c1, c2, c3);
        }
    } else {
        int i = tid - 256;              // 0..255
        int s = i & 15, kk = (i >> 4) & 7;
        int k = kg * KG + kk;
        int idx = k * (P_ * 16) + s;    // p = 0 slice -> relative offsets
        if (i < 128)
            bAi[kk * 16 + s] = (ac[idx] * 5 + ah[idx]) * ROWSTRIDE + aw[idx] * BPAD;
        else
            bBi[kk * 16 + s] = (bc[idx] * 5 + bh[idx]) * ROWSTRIDE + bw[idx] * BPAD;
    }
    __syncthreads();

    // ---- compute: wave wv -> k = kg*8 + wv
    const int k = kg * KG + wv;
    const int e = l >> 4;               // batch group (4 batches)

    float4 creg[S_];                    // leaf coefs in registers
#pragma unroll
    for (int s = 0; s < S_; ++s) creg[s] = cf[wv * 31 + s];

    int baseA[S_], baseB[S_];           // wave-uniform -> SGPR
#pragma unroll
    for (int s = 0; s < S_; ++s) {
        baseA[s] = __builtin_amdgcn_readfirstlane(bAi[wv * 16 + s]);
        baseB[s] = __builtin_amdgcn_readfirstlane(bBi[wv * 16 + s]);
    }

    const int obase = k * P_ + oh * OW_;

    for (int q = 0; q < 4; ++q) {
        int ow     = q * 16 + (l & 15);
        int ow_eff = ow < OW_ ? ow : OW_ - 1;   // helper lanes clamp (no store)
        int lo     = ow_eff * BPAD + e * 4;

        float v[4][S_];
#pragma unroll
        for (int s = 0; s < S_; ++s) {
            float4 av = *(const float4*)&xs[baseA[s] + lo];
            float4 bv = *(const float4*)&xs[baseB[s] + lo];
            float4 c  = creg[s];
            v[0][s] = fmaf(c.w, av.x * bv.x, fmaf(c.z, bv.x, fmaf(c.y, av.x, c.x)));
            v[1][s] = fmaf(c.w, av.y * bv.y, fmaf(c.z, bv.y, fmaf(c.y, av.y, c.x)));
            v[2][s] = fmaf(c.w, av.z * bv.z, fmaf(c.z, bv.z, fmaf(c.y, av.z, c.x)));
            v[3][s] = fmaf(c.w, av.w * bv.w, fmaf(c.z, bv.w, fmaf(c.y, av.w, c.x)));
        }
        // tree levels: level-outer, batch-inner so each cf read is hoisted
#pragma unroll
        for (int i = 0; i < 8; ++i) {
            float4 c = cf[wv * 31 + 16 + i];
#pragma unroll
            for (int j = 0; j < 4; ++j) {
                float a = v[j][2*i], b = v[j][2*i+1];
                v[j][i] = fmaf(c.w, a * b, fmaf(c.z, b, fmaf(c.y, a, c.x)));
            }
        }
#pragma unroll
        for (int i = 0; i < 4; ++i) {
            float4 c = cf[wv * 31 + 24 + i];
#pragma unroll
            for (int j = 0; j < 4; ++j) {
                float a = v[j][2*i], b = v[j][2*i+1];
                v[j][i] = fmaf(c.w, a * b, fmaf(c.z, b, fmaf(c.y, a, c.x)));
            }
        }
#pragma unroll
        for (int i = 0; i < 2; ++i) {
            float4 c = cf[wv * 31 + 28 + i];
#pragma unroll
            for (int j = 0; j < 4; ++j) {
                float a = v[j][2*i], b = v[j][2*i+1];
                v[j][i] = fmaf(c.w, a * b, fmaf(c.z, b, fmaf(c.y, a, c.x)));
            }
        }
        {
            float4 c = cf[wv * 31 + 30];
            if (ow < OW_) {
#pragma unroll
                for (int j = 0; j < 4; ++j) {
                    float a = v[j][0], b = v[j][1];
                    float r = fmaf(c.w, a * b, fmaf(c.z, b, fmaf(c.y, a, c.x)));
                    out[(size_t)(e * 4 + j) * (K_ * P_) + obase + ow] = r;
                }
            }
        }
    }
}

extern "C" void kernel_launch(void* const* d_in, const int* in_sizes, int n_in,
                              void* d_out, int out_size, void* d_ws, size_t ws_size,
                              hipStream_t stream) {
    const float* x  = (const float*)d_in[0];
    const int* ah = (const int*)d_in[1];
    const int* aw = (const int*)d_in[2];
    const int* ac = (const int*)d_in[3];
    const int* bh = (const int*)d_in[4];
    const int* bw = (const int*)d_in[5];
    const int* bc = (const int*)d_in[6];
    const float* w0 = (const float*)d_in[7];
    const float* w1 = (const float*)d_in[8];
    const float* w2 = (const float*)d_in[9];
    const float* w3 = (const float*)d_in[10];
    const float* w4 = (const float*)d_in[11];
    float* out = (float*)d_out;

    dim3 grid(OH_, NKG);
    logic_fused_kernel<<<grid, 512, 0, stream>>>(x, ah, aw, ac, bh, bw, bc,
                                                 w0, w1, w2, w3, w4, out);
}

// Round 6
// 26.154 us; speedup vs baseline: 1.2344x; 1.0022x over previous
//
#include <hip/hip_runtime.h>

#define B_   16
#define C_   3
#define H_   64
#define W_   64
#define K_   32
#define S_   16
#define OH_  60
#define OW_  60
#define P_   3600
#define IMG  (C_*H_*W_)

#define KG   8                  // k's per block
#define NKG  (K_/KG)            // 4 k-groups
#define ROWS (C_*5)             // 15 (c, rh) rows per oh-stripe
#define BPAD 20                 // padded batch stride in floats (16B-aligned slots,
                                // start-banks 4*{0,5,2,7,4,1,6,3} -> uniform)
#define ROWSTRIDE (W_*BPAD)     // 1280 floats
#define XLDS (ROWS*ROWSTRIDE)   // 19200 floats = 76.8 KB

__device__ __forceinline__ float gate(float4 c, float a, float b) {
    return fmaf(c.w, a * b, fmaf(c.z, b, fmaf(c.y, a, c.x)));
}

// Single fused kernel. Block (oh, kg): stage x-stripe (h=oh..oh+4, all c, all
// b) into LDS b-innermost; compute 8 k's coefs + base offsets in-block; then
// evaluate the gate tree. Wave wv owns k = kg*8+wv; lane = (ow 16, e 4),
// looping 4 ow-quadrants. Leaf + tree-level-1 fused to keep live regs ~150.
__global__ __launch_bounds__(512, 2) void logic_fused_kernel(
    const float* __restrict__ x,
    const int* __restrict__ ah, const int* __restrict__ aw, const int* __restrict__ ac,
    const int* __restrict__ bh, const int* __restrict__ bw, const int* __restrict__ bc,
    const float* __restrict__ w0, const float* __restrict__ w1,
    const float* __restrict__ w2, const float* __restrict__ w3,
    const float* __restrict__ w4,
    float* __restrict__ out)
{
    __shared__ float  xs[XLDS];
    __shared__ float4 cf[KG * 31];
    __shared__ int    bAi[KG * S_], bBi[KG * S_];

    const int oh  = blockIdx.x;
    const int kg  = blockIdx.y;
    const int tid = threadIdx.x;
    const int l   = tid & 63;
    const int wv  = tid >> 6;           // 0..7

    // ---- stage x stripe: 240 jobs (row=c*5+dh, b); 1 coalesced 256B read each
    for (int job = wv; job < ROWS * B_; job += 8) {
        int b   = job & 15;
        int row = job >> 4;             // c*5 + dh, 0..14
        int c   = row / 5, dh = row - c * 5;
        float v = x[((b * C_ + c) * H_ + (oh + dh)) * W_ + l];
        xs[row * ROWSTRIDE + l * BPAD + b] = v;
    }

    // ---- coefs (threads 0..255) and base offsets (threads 256..511)
    if (tid < 256) {
        int node = tid & 31, kk = tid >> 5;
        if (node < 31) {
            int k = kg * KG + kk;
            const float* w; int i;
            if      (node < 16) { w = w0; i = node;      }
            else if (node < 24) { w = w1; i = node - 16; }
            else if (node < 28) { w = w2; i = node - 24; }
            else if (node < 30) { w = w3; i = node - 28; }
            else                { w = w4; i = 0;         }
            const float* src = w + ((size_t)i * K_ + k) * 16;
            float lg[16];
            float m = -1e30f;
#pragma unroll
            for (int s = 0; s < 16; ++s) { lg[s] = src[s]; m = fmaxf(m, lg[s]); }
            float sum = 0.f;
#pragma unroll
            for (int s = 0; s < 16; ++s) { lg[s] = expf(lg[s] - m); sum += lg[s]; }
            float inv = 1.f / sum;
            const float M[16][4] = {
                {0,0,0,0},{0,0,0,1},{0,1,0,-1},{0,1,0,0},
                {0,0,1,-1},{0,0,1,0},{0,1,1,-2},{0,1,1,-1},
                {1,-1,-1,1},{1,-1,-1,2},{1,0,-1,0},{1,0,-1,1},
                {1,-1,0,0},{1,-1,0,1},{1,0,0,-1},{1,0,0,0}};
            float c0 = 0.f, c1 = 0.f, c2 = 0.f, c3 = 0.f;
#pragma unroll
            for (int s = 0; s < 16; ++s) {
                float pr = lg[s] * inv;
                c0 += pr * M[s][0]; c1 += pr * M[s][1];
                c2 += pr * M[s][2]; c3 += pr * M[s][3];
            }
            cf[kk * 31 + node] = make_float4(c0, c1, c2, c3);
        }
    } else {
        int i = tid - 256;              // 0..255
        int s = i & 15, kk = (i >> 4) & 7;
        int k = kg * KG + kk;
        int idx = k * (P_ * 16) + s;    // p = 0 slice -> relative offsets
        if (i < 128)
            bAi[kk * 16 + s] = (ac[idx] * 5 + ah[idx]) * ROWSTRIDE + aw[idx] * BPAD;
        else
            bBi[kk * 16 + s] = (bc[idx] * 5 + bh[idx]) * ROWSTRIDE + bw[idx] * BPAD;
    }
    __syncthreads();

    // ---- compute: wave wv -> k = kg*8 + wv
    const int k = kg * KG + wv;
    const int e = l >> 4;               // batch group (4 batches)

    float4 creg[S_];                    // leaf coefs in registers (64 VGPR)
#pragma unroll
    for (int s = 0; s < S_; ++s) creg[s] = cf[wv * 31 + s];

    int baseA[S_], baseB[S_];           // wave-uniform -> SGPR
#pragma unroll
    for (int s = 0; s < S_; ++s) {
        baseA[s] = __builtin_amdgcn_readfirstlane(bAi[wv * 16 + s]);
        baseB[s] = __builtin_amdgcn_readfirstlane(bBi[wv * 16 + s]);
    }

    const int obase = k * P_ + oh * OW_;

    for (int q = 0; q < 4; ++q) {
        int ow     = q * 16 + (l & 15);
        int ow_eff = ow < OW_ ? ow : OW_ - 1;   // helper lanes clamp (no store)
        int lo     = ow_eff * BPAD + e * 4;

        float t[4][8];                  // after fused leaf+level-1 (32 VGPR)
#pragma unroll
        for (int i = 0; i < 8; ++i) {
            float4 a0 = *(const float4*)&xs[baseA[2*i]   + lo];
            float4 b0 = *(const float4*)&xs[baseB[2*i]   + lo];
            float4 a1 = *(const float4*)&xs[baseA[2*i+1] + lo];
            float4 b1 = *(const float4*)&xs[baseB[2*i+1] + lo];
            float4 c0 = creg[2*i], c1 = creg[2*i+1];
            float4 d  = cf[wv * 31 + 16 + i];
            {
                float la = gate(c0, a0.x, b0.x), lb = gate(c1, a1.x, b1.x);
                t[0][i] = gate(d, la, lb);
            }
            {
                float la = gate(c0, a0.y, b0.y), lb = gate(c1, a1.y, b1.y);
                t[1][i] = gate(d, la, lb);
            }
            {
                float la = gate(c0, a0.z, b0.z), lb = gate(c1, a1.z, b1.z);
                t[2][i] = gate(d, la, lb);
            }
            {
                float la = gate(c0, a0.w, b0.w), lb = gate(c1, a1.w, b1.w);
                t[3][i] = gate(d, la, lb);
            }
        }
        // level 2 (nodes 24..27)
#pragma unroll
        for (int i = 0; i < 4; ++i) {
            float4 c = cf[wv * 31 + 24 + i];
#pragma unroll
            for (int j = 0; j < 4; ++j)
                t[j][i] = gate(c, t[j][2*i], t[j][2*i+1]);
        }
        // level 3 (nodes 28..29)
#pragma unroll
        for (int i = 0; i < 2; ++i) {
            float4 c = cf[wv * 31 + 28 + i];
#pragma unroll
            for (int j = 0; j < 4; ++j)
                t[j][i] = gate(c, t[j][2*i], t[j][2*i+1]);
        }
        // root (node 30) + store
        {
            float4 c = cf[wv * 31 + 30];
            if (ow < OW_) {
#pragma unroll
                for (int j = 0; j < 4; ++j) {
                    float r = gate(c, t[j][0], t[j][1]);
                    out[(size_t)(e * 4 + j) * (K_ * P_) + obase + ow] = r;
                }
            }
        }
    }
}

extern "C" void kernel_launch(void* const* d_in, const int* in_sizes, int n_in,
                              void* d_out, int out_size, void* d_ws, size_t ws_size,
                              hipStream_t stream) {
    const float* x  = (const float*)d_in[0];
    const int* ah = (const int*)d_in[1];
    const int* aw = (const int*)d_in[2];
    const int* ac = (const int*)d_in[3];
    const int* bh = (const int*)d_in[4];
    const int* bw = (const int*)d_in[5];
    const int* bc = (const int*)d_in[6];
    const float* w0 = (const float*)d_in[7];
    const float* w1 = (const float*)d_in[8];
    const float* w2 = (const float*)d_in[9];
    const float* w3 = (const float*)d_in[10];
    const float* w4 = (const float*)d_in[11];
    float* out = (float*)d_out;

    dim3 grid(OH_, NKG);
    logic_fused_kernel<<<grid, 512, 0, stream>>>(x, ah, aw, ac, bh, bw, bc,
                                                 w0, w1, w2, w3, w4, out);
}